// Round 1
// 270.442 us; speedup vs baseline: 1.0493x; 1.0493x over previous
//
#include <hip/hip_runtime.h>
#include <hip/hip_bf16.h>
#include <stdint.h>
#include <cmath>

// IDXST_IDCT on MI355X: y = S · x · C^T with
//   C[v,q] = cos(pi*q*(2v+1)/(2N)),  S[u,p] = sin(pi*p*(2u+1)/(2M))
// Butterfly halves GEMM FLOPs (dual E/O accumulators, fused epilogue).
// R8: pipeline restructure. BM=128 x BN=256 x BK=64, 512 threads (8 waves,
// 2m x 4n, 64x64 per wave), grid 16x16 = 256 blocks = 1/CU.
// The E/O parity pair IS the software pipeline: while computing parity P
// from its LDS buffers, the other parity's next tiles are in flight via
// global_load_lds; __syncthreads()'s vmcnt(0) drain then lands loads that
// were issued a full phase earlier (T3-minimum schedule, plain HIP).
// XOR-swizzled LDS (verified zero bank conflicts), XCD-aware block swizzle.
// 3 dispatches total: prep, F1 (GEMM+bfly1+deint), F2 (GEMM+bfly2).

typedef __attribute__((ext_vector_type(4))) float f32x4;
typedef __attribute__((ext_vector_type(8))) unsigned short u16x8;
typedef __attribute__((ext_vector_type(8))) __bf16 bf16x8;

__device__ __forceinline__ unsigned short f2bf(float f) {
  union { float f; unsigned u; } v; v.f = f;
  unsigned u = v.u + 0x7fffu + ((v.u >> 16) & 1u);  // RNE
  return (unsigned short)(u >> 16);
}

// ---- gen device helper: half transform matrices [L/2 x L/2] bf16 ----
// Pe[i,j] = f(pi*(2j)(2i+1)/(2L)), Po[i,j] = f(pi*(2j+1)(2i+1)/(2L)).
// r tracked mod 4L (power of two -> exact in u32).
__device__ __forceinline__ void gen_half(int idx, u16x8* Pe, u16x8* Po,
                                         int isSin, int jshift, int jmask,
                                         unsigned mask4L, float sc) {
  int i = idx >> jshift;           // row
  int jb = (idx & jmask) * 8;      // first col
  unsigned tp = 2u * (unsigned)i + 1u;
  unsigned re = (2u * (unsigned)jb * tp) & mask4L;
  unsigned ro = (re + tp) & mask4L;
  unsigned step = (2u * tp) & mask4L;
  u16x8 pe, po;
#pragma unroll
  for (int t = 0; t < 8; t++) {
    float se_, ce_, so_, co_;
    __sincosf((float)re * sc, &se_, &ce_);
    __sincosf((float)ro * sc, &so_, &co_);
    pe[t] = f2bf(isSin ? se_ : ce_);
    po[t] = f2bf(isSin ? so_ : co_);
    re = (re + step) & mask4L;
    ro = (ro + step) & mask4L;
  }
  Pe[idx] = pe;
  Po[idx] = po;
}

// ---- single prep dispatch: convert+deint | gen Ce/Co | gen Se/So ----
__global__ void prep_kernel(const f32x4* __restrict__ x, u16x8* __restrict__ xe,
                            u16x8* __restrict__ xo, u16x8* __restrict__ Ce,
                            u16x8* __restrict__ Co, u16x8* __restrict__ Se,
                            u16x8* __restrict__ So, int nConvBlocks,
                            int nGenNBlocks, int jshiftN, int jmaskN,
                            unsigned mask4N, float scN, int jshiftM, int jmaskM,
                            unsigned mask4M, float scM) {
  int b = blockIdx.x;
  if (b < nConvBlocks) {
    int idx = b * 256 + threadIdx.x;
    f32x4 a = x[4 * idx], bb = x[4 * idx + 1], c = x[4 * idx + 2],
          d = x[4 * idx + 3];
    u16x8 e, o;
    e[0] = f2bf(a[0]);  o[0] = f2bf(a[1]);  e[1] = f2bf(a[2]);  o[1] = f2bf(a[3]);
    e[2] = f2bf(bb[0]); o[2] = f2bf(bb[1]); e[3] = f2bf(bb[2]); o[3] = f2bf(bb[3]);
    e[4] = f2bf(c[0]);  o[4] = f2bf(c[1]);  e[5] = f2bf(c[2]);  o[5] = f2bf(c[3]);
    e[6] = f2bf(d[0]);  o[6] = f2bf(d[1]);  e[7] = f2bf(d[2]);  o[7] = f2bf(d[3]);
    xe[idx] = e;
    xo[idx] = o;
  } else if (b < nConvBlocks + nGenNBlocks) {
    int idx = (b - nConvBlocks) * 256 + threadIdx.x;
    gen_half(idx, Ce, Co, 0, jshiftN, jmaskN, mask4N, scN);
  } else {
    int idx = (b - nConvBlocks - nGenNBlocks) * 256 + threadIdx.x;
    gen_half(idx, Se, So, 1, jshiftM, jmaskM, mask4M, scM);
  }
}

// ---- fused dual bt-GEMM + butterfly epilogue, E/O-pipelined ----
// accE[m,n] = sum_k Ae[m,k]*Be[n,k]; accO likewise with Ao/Bo.
// BM=128, BN=256, BK=64, 512 threads (8 waves of 64x64; 2m x 4n).
// LDS: elem (row,col) at row*64 + ((col/8)^(row&7))*8 + col%8; staging lane l
// sources global col ((l&7)^(l>>3))*8 so dst stays wave-uniform-base+lane*16.
// Per K-step: phase-E {prefetch O(k); read E frags; 32 MFMA; sync} then
// phase-O {prefetch E(k+1); read O frags; 32 MFMA; sync}. Each prefetch gets
// one full phase of compute cover before the barrier's vmcnt(0) drain.
// STAGE==1 (m=v, n=p): (p&1?out1:out0)[v, p>>1] = E+O;
//                      [...][Lfull-1-v, p>>1]   = E-O   (bf16)
// STAGE==2 (m=u, n=v): y[u,v] = E+O; y[Lfull-1-u,v] = O-E  (fp32, out0)
template <int STAGE>
__global__ __launch_bounds__(512, 2) void fused_gemm_kernel(
    const unsigned short* __restrict__ Ae,
    const unsigned short* __restrict__ Ao,
    const unsigned short* __restrict__ Be,
    const unsigned short* __restrict__ Bo,
    unsigned short* __restrict__ out0, unsigned short* __restrict__ out1,
    int outStride, int K, int Lfull) {
  __shared__ unsigned short AsE[128 * 64];
  __shared__ unsigned short BsE[256 * 64];
  __shared__ unsigned short AsO[128 * 64];
  __shared__ unsigned short BsO[256 * 64];

  const int tid = threadIdx.x;

  // XCD-aware bijective block swizzle (nwg = 256, nwg%8 == 0).
  const int nwg = gridDim.x * gridDim.y;
  const int lin = blockIdx.y * gridDim.x + blockIdx.x;
  int swb = lin;
  if ((nwg & 7) == 0) swb = (lin & 7) * (nwg >> 3) + (lin >> 3);
  const int m0 = (swb / gridDim.x) * 128;
  const int n0 = (swb % gridDim.x) * 256;

  const int wave = tid >> 6;
  const int lane = tid & 63;
  const int wm = (wave >> 2) * 64;   // 2 m-waves
  const int wn = (wave & 3) * 64;    // 4 n-waves
  const int l16 = lane & 15;
  const int quad = lane >> 4;
  const int swz = (quad ^ (l16 & 7)) * 8;  // frag col swizzle, k-half 0

  // staging: each wave loads A-chunks {w, w+8} and B-chunks {w,+8,+16,+24};
  // chunk = 8 rows x 64 cols = 1 KB = one wave-wide global_load_lds.
  const int lrow = lane >> 3;                // row within chunk
  const int lsw = ((lane & 7) ^ lrow) * 8;   // swizzled source col (elems)

  auto stage = [&](const unsigned short* __restrict__ A,
                   const unsigned short* __restrict__ B, unsigned short* As,
                   unsigned short* Bs, int k0) {
    const unsigned short* Ap =
        A + (size_t)(m0 + 8 * wave + lrow) * K + lsw + k0;
    const unsigned short* Bp =
        B + (size_t)(n0 + 8 * wave + lrow) * K + lsw + k0;
    unsigned short* Adst = As + wave * 512;
    unsigned short* Bdst = Bs + wave * 512;
#define GLL(src, dst)                                                        \
  __builtin_amdgcn_global_load_lds(                                          \
      (const __attribute__((address_space(1))) void*)(src),                  \
      (__attribute__((address_space(3))) void*)(dst), 16, 0, 0)
    GLL(Ap, Adst);
    GLL(Ap + (size_t)64 * K, Adst + 4096);
    GLL(Bp, Bdst);
    GLL(Bp + (size_t)64 * K, Bdst + 4096);
    GLL(Bp + (size_t)128 * K, Bdst + 8192);
    GLL(Bp + (size_t)192 * K, Bdst + 12288);
#undef GLL
  };

  f32x4 accE[4][4], accO[4][4];
#pragma unroll
  for (int i = 0; i < 4; i++)
#pragma unroll
    for (int j = 0; j < 4; j++) {
      accE[i][j] = f32x4{0.f, 0.f, 0.f, 0.f};
      accO[i][j] = f32x4{0.f, 0.f, 0.f, 0.f};
    }

  auto phase = [&](const unsigned short* As, const unsigned short* Bs,
                   f32x4 (&acc)[4][4]) {
#pragma unroll
    for (int h = 0; h < 2; h++) {
      const int so = swz ^ (h * 32);
      bf16x8 af[4], bfr[4];
#pragma unroll
      for (int i = 0; i < 4; i++)
        af[i] = *(const bf16x8*)(As + (wm + i * 16 + l16) * 64 + so);
#pragma unroll
      for (int j = 0; j < 4; j++)
        bfr[j] = *(const bf16x8*)(Bs + (wn + j * 16 + l16) * 64 + so);
#pragma unroll
      for (int i = 0; i < 4; i++)
#pragma unroll
        for (int j = 0; j < 4; j++)
          acc[i][j] = __builtin_amdgcn_mfma_f32_16x16x32_bf16(
              af[i], bfr[j], acc[i][j], 0, 0, 0);
    }
  };

  // prologue: E(0) staged and drained
  stage(Ae, Be, AsE, BsE, 0);
  __syncthreads();

  for (int k0 = 0; k0 < K; k0 += 64) {
    // phase E: prefetch O(k0) under E's compute
    stage(Ao, Bo, AsO, BsO, k0);
    phase(AsE, BsE, accE);
    __syncthreads();  // drains O(k0) loads; frees E buffers
    // phase O: prefetch E(k0+64) under O's compute
    if (k0 + 64 < K) stage(Ae, Be, AsE, BsE, k0 + 64);
    phase(AsO, BsO, accO);
    __syncthreads();  // drains E(k0+64) loads; frees O buffers
  }

  // epilogue: D row = quad*4 + reg, col = lane&15; butterfly E/O in fp32
#pragma unroll
  for (int i = 0; i < 4; i++) {
#pragma unroll
    for (int j = 0; j < 4; j++) {
      int n = n0 + wn + j * 16 + l16;
      int mb = m0 + wm + i * 16 + quad * 4;
#pragma unroll
      for (int r = 0; r < 4; r++) {
        float e = accE[i][j][r];
        float o = accO[i][j][r];
        int m = mb + r;
        if (STAGE == 1) {
          unsigned short* mat = (n & 1) ? out1 : out0;
          int c = n >> 1;
          mat[(size_t)m * outStride + c] = f2bf(e + o);
          mat[(size_t)(Lfull - 1 - m) * outStride + c] = f2bf(e - o);
        } else {
          float* y = (float*)out0;
          y[(size_t)m * outStride + n] = e + o;
          y[(size_t)(Lfull - 1 - m) * outStride + n] = o - e;
        }
      }
    }
  }
}

extern "C" void kernel_launch(void* const* d_in, const int* in_sizes, int n_in,
                              void* d_out, int out_size, void* d_ws,
                              size_t ws_size, hipStream_t stream) {
  const float* x = (const float*)d_in[0];
  const int M = in_sizes[1] / 2;  // expkM is [M,2]
  const int N = in_sizes[2] / 2;  // expkN is [N,2]
  const size_t MN = (size_t)M * N;

  // workspace (u16 units), 3*MN u16 = 96 MB @4096:
  //  [0, MN/2)      xe  [M x N/2]
  //  [MN/2, MN)     xo  [M x N/2]
  //  [MN, 5MN/4)    Ce ; [5MN/4, 3MN/2) Co     [N/2 x N/2]
  //  [3MN/2, 7MN/4) Se ; [7MN/4, 2MN)   So     [M/2 x M/2]
  //  [2MN, 5MN/2)   tTe [N x M/2]
  //  [5MN/2, 3MN)   tTo [N x M/2]
  unsigned short* ws = (unsigned short*)d_ws;
  unsigned short* xe = ws;
  unsigned short* xo = ws + MN / 2;
  unsigned short* Ce = ws + MN;
  unsigned short* Co = ws + MN + MN / 4;
  unsigned short* Se = ws + MN * 3 / 2;
  unsigned short* So = ws + MN * 7 / 4;
  unsigned short* tTe = ws + MN * 2;
  unsigned short* tTo = ws + MN * 5 / 2;

  int shiftN = 0; while ((1 << shiftN) < N) shiftN++;
  int shiftM = 0; while ((1 << shiftM) < M) shiftM++;

  // 1: fused prep — convert+deint, gen Ce/Co, gen Se/So
  int nConvBlocks = (int)(MN / 16 / 256);
  int nGenNBlocks = (N / 2) * (N / 2) / 8 / 256;
  int nGenMBlocks = (M / 2) * (M / 2) / 8 / 256;
  prep_kernel<<<nConvBlocks + nGenNBlocks + nGenMBlocks, 256, 0, stream>>>(
      (const f32x4*)x, (u16x8*)xe, (u16x8*)xo, (u16x8*)Ce, (u16x8*)Co,
      (u16x8*)Se, (u16x8*)So, nConvBlocks, nGenNBlocks, shiftN - 4,
      (N / 16) - 1, (unsigned)(4 * N - 1),
      (float)(3.14159265358979323846 / (2.0 * N)), shiftM - 4, (M / 16) - 1,
      (unsigned)(4 * M - 1), (float)(3.14159265358979323846 / (2.0 * M)));

  // 2: F1 — E/O GEMMs (K=N/2) + v-butterfly + p-parity deint -> tTe/tTo
  //    grid: x over p (M/256), y over v' ((N/2)/128); 512 threads
  fused_gemm_kernel<1><<<dim3(M / 256, (N / 2) / 128), 512, 0, stream>>>(
      Ce, Co, xe, xo, tTe, tTo, M / 2, N / 2, N);

  // 3: F2 — E/O GEMMs (K=M/2) + u-butterfly -> y fp32
  //    grid: x over v (N/256), y over u' ((M/2)/128); 512 threads
  fused_gemm_kernel<2><<<dim3(N / 256, (M / 2) / 128), 512, 0, stream>>>(
      Se, So, tTe, tTo, (unsigned short*)d_out, nullptr, N, M / 2, M);
}